// Round 7
// baseline (247.967 us; speedup 1.0000x reference)
//
#include <hip/hip_runtime.h>
#include <hip/hip_bf16.h>
#include <stdint.h>

#define IN_F 128
#define OUT_F 16
#define NEG_SLOPE 0.2f
#define SB_BITS 9               // super-bucket = 512 nodes (scatter granularity)
#define SB_NODES 512
#define NBS 196                 // ceil(100000/512); super-bucket count
#define CAP_SB 17408            // mean 16384, sigma ~128 -> +8 sigma
#define TILE_NODES 128          // agg output tile
#define LCAP 4608               // per-128-node-slice capacity (mean 4092)
#define SC_E 4096               // edges per scatter block
#define W_LD (IN_F + 4)         // pad: 132%32==4 -> 2-way (free); 128 was 16-way

// ---------------------------------------------------------------------------
// Projection: hW = h @ W^T  [N,16], el = hW @ a_l^T, er = hW @ a_r^T
// ---------------------------------------------------------------------------
__global__ __launch_bounds__(256) void proj_kernel(
    const float* __restrict__ h, const float* __restrict__ W,
    const float* __restrict__ a_l, const float* __restrict__ a_r,
    float* __restrict__ hW, float* __restrict__ el, float* __restrict__ er,
    int N) {
  __shared__ float Ws[OUT_F * W_LD];
  for (int i = threadIdx.x; i < OUT_F * IN_F; i += blockDim.x)
    Ws[(i >> 7) * W_LD + (i & (IN_F - 1))] = W[i];
  __syncthreads();

  int gid = blockIdx.x * blockDim.x + threadIdx.x;
  int node = gid >> 4;
  int feat = gid & 15;
  if (node >= N) return;

  const float4* hrow = (const float4*)(h + (size_t)node * IN_F);
  const float4* wrow = (const float4*)(&Ws[feat * W_LD]);
  float acc = 0.f;
#pragma unroll
  for (int k = 0; k < IN_F / 4; ++k) {
    float4 hv = hrow[k];
    float4 wv = wrow[k];
    acc += hv.x * wv.x + hv.y * wv.y + hv.z * wv.z + hv.w * wv.w;
  }
  hW[node * OUT_F + feat] = acc;

  float vl = acc * a_l[feat];
  float vr = acc * a_r[feat];
#pragma unroll
  for (int off = 8; off; off >>= 1) {
    vl += __shfl_down(vl, off, 16);
    vr += __shfl_down(vr, off, 16);
  }
  if (feat == 0) {
    el[node] = vl;
    er[node] = vr;
  }
}

// ---------------------------------------------------------------------------
// Scatter into 512-node super-buckets: LDS counting-sort by dst>>9, one
// global atomic per (block, nonempty super-bucket) [196 bins -> 153K total
// atomics vs r6's 611K], coalesced run write-out (avg run 21 edges = 168 B).
// Payload 4 B: (src << 9) | (dst & 511).
// ---------------------------------------------------------------------------
__global__ __launch_bounds__(256) void scatter_kernel(
    const int* __restrict__ src, const int* __restrict__ dst,
    int* __restrict__ cursor, uint32_t* __restrict__ payload,
    int E) {
  __shared__ int hist[NBS];
  __shared__ int pref[NBS];
  __shared__ int gbase[NBS];
  __shared__ int rank[NBS];
  __shared__ uint32_t sortedP[SC_E];  // 16 KB
  __shared__ uint8_t sortedB[SC_E];   // 4 KB (NBS=196 < 256)

  int t = threadIdx.x;
  int start = blockIdx.x * SC_E;
  int end = min(E, start + SC_E);
  int cnt = end - start;

  if (t < NBS) { hist[t] = 0; rank[t] = 0; }
  __syncthreads();

  for (int i = start + t; i < end; i += 256)
    atomicAdd(&hist[dst[i] >> SB_BITS], 1);
  __syncthreads();

  if (t == 0) {  // serial exclusive prefix over 196 bins (~1.6K cycles)
    int run = 0;
    for (int b = 0; b < NBS; ++b) {
      pref[b] = run;
      run += hist[b];
    }
  }
  __syncthreads();
  if (t < NBS) {
    int c = hist[t];
    gbase[t] = c ? atomicAdd(&cursor[t * 16], c) : 0;  // cursor pre-zeroed
  }
  __syncthreads();

  for (int i = start + t; i < end; i += 256) {
    int d = dst[i];
    int s = src[i];
    int b = d >> SB_BITS;
    int r = atomicAdd(&rank[b], 1);
    int pos = pref[b] + r;
    sortedP[pos] = ((uint32_t)s << SB_BITS) | (uint32_t)(d & (SB_NODES - 1));
    sortedB[pos] = (uint8_t)b;
  }
  __syncthreads();

  for (int i = t; i < cnt; i += 256) {
    int b = sortedB[i];
    int ofs = gbase[b] + (i - pref[b]);
    if (ofs < CAP_SB) payload[(size_t)b * CAP_SB + ofs] = sortedP[i];  // never hit
  }
}

// ---------------------------------------------------------------------------
// Fused sort+aggregate: block b owns 128-node tile, scans super-bucket b>>2's
// payload (coalesced, L2-hot) keeping the quarter matching slice b&3.
// Pass 1: hist; pass 2 (re-read): place into LDS sorted; then 16-lane-group
// register CSR aggregation with fused normalize. No raw[] staging (20 KB LDS).
// ---------------------------------------------------------------------------
__global__ __launch_bounds__(512) void agg_kernel(
    const uint32_t* __restrict__ payload, const int* __restrict__ cursor,
    const float* __restrict__ hW, const float* __restrict__ el,
    const float* __restrict__ er, float* __restrict__ out, int N) {
  __shared__ uint32_t sorted[LCAP];  // 18 KB
  __shared__ int hist[TILE_NODES];
  __shared__ int pref[TILE_NODES];
  __shared__ int rank[TILE_NODES];

  int t = threadIdx.x;
  int b = blockIdx.x;
  int sb = b >> 2;
  int quad = b & 3;
  size_t base = (size_t)sb * CAP_SB;
  int cnt = min(cursor[sb * 16], CAP_SB);

  if (t < TILE_NODES) { hist[t] = 0; rank[t] = 0; }
  __syncthreads();

  for (int i = t; i < cnt; i += 512) {
    uint32_t p = payload[base + i];
    if ((int)((p >> 7) & 3) == quad) atomicAdd(&hist[p & (TILE_NODES - 1)], 1);
  }
  __syncthreads();

  if (t < TILE_NODES) {  // 128-thread O(n) prefix
    int s = 0;
    for (int j = 0; j < t; ++j) s += hist[j];
    pref[t] = s;
  }
  __syncthreads();

  for (int i = t; i < cnt; i += 512) {  // re-read (L2-hot) and place
    uint32_t p = payload[base + i];
    if ((int)((p >> 7) & 3) == quad) {
      int dl = (int)(p & (TILE_NODES - 1));
      int r = atomicAdd(&rank[dl], 1);
      int pos = pref[dl] + r;
      if (pos < LCAP) sorted[pos] = p;  // never hit
    }
  }
  __syncthreads();

  int g = t >> 4;  // 32 groups of 16 lanes
  int f = t & 15;
  int node0 = b * TILE_NODES;
  for (int dl = g; dl < TILE_NODES; dl += 32) {
    int node = node0 + dl;
    if (node >= N) break;
    float erd = er[node];
    int k = pref[dl];
    int kend = k + hist[dl];
    float acc = 0.f;
    float es = 0.f;
#pragma unroll 4
    for (; k < kend; ++k) {
      uint32_t p = sorted[k];
      int s = (int)(p >> SB_BITS);
      float x = el[s] + erd;
      x = x > 0.f ? x : NEG_SLOPE * x;
      float ex = __expf(x);
      acc += ex * hW[s * OUT_F + f];
      es += ex;
    }
    out[(size_t)node * OUT_F + f] = acc / fmaxf(es, 1e-16f);
  }
}

extern "C" void kernel_launch(void* const* d_in, const int* in_sizes, int n_in,
                              void* d_out, int out_size, void* d_ws, size_t ws_size,
                              hipStream_t stream) {
  const float* h   = (const float*)d_in[0];
  const int*   src = (const int*)d_in[1];
  const int*   dst = (const int*)d_in[2];
  const float* W   = (const float*)d_in[3];
  const float* a_l = (const float*)d_in[4];
  const float* a_r = (const float*)d_in[5];
  float* out = (float*)d_out;

  const int N = in_sizes[0] / IN_F;
  const int E = in_sizes[1];

  // ws: hW | el | er | cursor | payload
  float* ws = (float*)d_ws;
  float* hW = ws;                                  // N*16
  float* el = hW + (size_t)N * OUT_F;              // N
  float* er = el + N;                              // N
  int* cursor = (int*)(er + N);                    // NBS*16 (line-strided)
  uint32_t* payload = (uint32_t*)(cursor + (size_t)NBS * 16);  // NBS*CAP_SB*4 B

  hipMemsetAsync(cursor, 0, (size_t)NBS * 16 * sizeof(int), stream);

  {
    int total = N * OUT_F;
    proj_kernel<<<(total + 255) / 256, 256, 0, stream>>>(h, W, a_l, a_r, hW, el,
                                                         er, N);
  }
  {
    int blocks = (E + SC_E - 1) / SC_E;
    scatter_kernel<<<blocks, 256, 0, stream>>>(src, dst, cursor, payload, E);
  }
  {
    int tiles = (N + TILE_NODES - 1) / TILE_NODES;
    agg_kernel<<<tiles, 512, 0, stream>>>(payload, cursor, hW, el, er, out, N);
  }
}

// Round 8
// 211.614 us; speedup vs baseline: 1.1718x; 1.1718x over previous
//
#include <hip/hip_runtime.h>
#include <hip/hip_bf16.h>
#include <stdint.h>

#define IN_F 128
#define OUT_F 16
#define NEG_SLOPE 0.2f
#define SB_BITS 9               // super-bucket = 512 nodes (scatter granularity)
#define SB_NODES 512
#define NBS 196                 // ceil(100000/512)
#define CAP_SB 17408            // mean 16366, sigma ~127 -> +8 sigma
#define TILE_NODES 128          // agg output tile (quad of an SB)
#define LCAP 4608               // per-quad capacity (mean 4092, +8 sigma)
#define SC_E 4096               // edges per scatter block
#define W_LD (IN_F + 4)         // pad: 132%32==4 -> 2-way (free); 128 was 16-way
#define SB_SPACING 200          // 200%8==0 -> all 4 quads of an SB on same XCD

// scatter LDS: hist/pref/gbase/rank (4*196*4=3136) + sortedP 16K + sortedB 4K
#define SMEM_BYTES (3136 + 16384 + 4096)

// ---------------------------------------------------------------------------
// Fused proj + scatter (independent work; one dispatch, overlapped HBM streams)
// blocks [0, 782): scatter into 512-node super-buckets — LDS counting-sort by
//   dst>>9, one global atomic per (block,bucket) range reservation, coalesced
//   run write-out. Payload 4 B: (src<<9) | (dst&511).
// blocks [782, 782+6250): projection hW = h@W^T, el/er logits.
// ---------------------------------------------------------------------------
__global__ __launch_bounds__(256) void proj_scatter_kernel(
    const float* __restrict__ h, const float* __restrict__ W,
    const float* __restrict__ a_l, const float* __restrict__ a_r,
    const int* __restrict__ src, const int* __restrict__ dst,
    float* __restrict__ hW, float* __restrict__ el, float* __restrict__ er,
    int* __restrict__ cursor, uint32_t* __restrict__ payload,
    int N, int E, int scatBlocks) {
  __shared__ __align__(16) uint8_t smem[SMEM_BYTES];
  int t = threadIdx.x;

  if ((int)blockIdx.x < scatBlocks) {
    // ---------------- scatter branch ----------------
    int* hist = (int*)smem;          // NBS
    int* pref = hist + NBS;
    int* gbase = pref + NBS;
    int* rank = gbase + NBS;
    uint32_t* sortedP = (uint32_t*)(smem + 3136);
    uint8_t* sortedB = smem + 3136 + 16384;

    int start = blockIdx.x * SC_E;
    int end = min(E, start + SC_E);
    int cnt = end - start;

    if (t < NBS) { hist[t] = 0; rank[t] = 0; }
    __syncthreads();

    for (int i = start + t; i < end; i += 256)
      atomicAdd(&hist[dst[i] >> SB_BITS], 1);
    __syncthreads();

    if (t == 0) {  // serial exclusive prefix over 196 bins
      int run = 0;
      for (int b = 0; b < NBS; ++b) {
        pref[b] = run;
        run += hist[b];
      }
    }
    __syncthreads();
    if (t < NBS) {
      int c = hist[t];
      gbase[t] = c ? atomicAdd(&cursor[t * 16], c) : 0;  // cursor pre-zeroed
    }
    __syncthreads();

    for (int i = start + t; i < end; i += 256) {
      int d = dst[i];
      int s = src[i];
      int b = d >> SB_BITS;
      int r = atomicAdd(&rank[b], 1);
      int pos = pref[b] + r;
      sortedP[pos] = ((uint32_t)s << SB_BITS) | (uint32_t)(d & (SB_NODES - 1));
      sortedB[pos] = (uint8_t)b;
    }
    __syncthreads();

    for (int i = t; i < cnt; i += 256) {
      int b = sortedB[i];
      int ofs = gbase[b] + (i - pref[b]);
      if (ofs < CAP_SB) payload[(size_t)b * CAP_SB + ofs] = sortedP[i];
    }
  } else {
    // ---------------- projection branch ----------------
    float* Ws = (float*)smem;  // OUT_F * W_LD = 8448 B < SMEM_BYTES
    for (int i = t; i < OUT_F * IN_F; i += 256)
      Ws[(i >> 7) * W_LD + (i & (IN_F - 1))] = W[i];
    __syncthreads();

    int gid = ((int)blockIdx.x - scatBlocks) * 256 + t;
    int node = gid >> 4;
    int feat = gid & 15;
    if (node >= N) return;

    const float4* hrow = (const float4*)(h + (size_t)node * IN_F);
    const float4* wrow = (const float4*)(&Ws[feat * W_LD]);
    float acc = 0.f;
#pragma unroll
    for (int k = 0; k < IN_F / 4; ++k) {
      float4 hv = hrow[k];
      float4 wv = wrow[k];
      acc += hv.x * wv.x + hv.y * wv.y + hv.z * wv.z + hv.w * wv.w;
    }
    hW[node * OUT_F + feat] = acc;

    float vl = acc * a_l[feat];
    float vr = acc * a_r[feat];
#pragma unroll
    for (int off = 8; off; off >>= 1) {
      vl += __shfl_down(vl, off, 16);
      vr += __shfl_down(vr, off, 16);
    }
    if (feat == 0) {
      el[node] = vl;
      er[node] = vr;
    }
  }
}

// ---------------------------------------------------------------------------
// Fused sort+aggregate. blockIdx = quad*SB_SPACING + sb so all 4 quads of a
// super-bucket land on one XCD (blockIdx%8 equal) -> the 8 payload scans hit
// L2 after the first fetch (r7: 8x HBM re-reads = 142 MB FETCH). Scans are
// uint4-vectorized. After LDS counting-sort, exp(leaky_relu(..)) is computed
// ONCE per edge into exS[] (r7 recomputed it on all 16 lanes), then 16-lane
// groups do register CSR aggregation + fused normalize. No global atomics.
// ---------------------------------------------------------------------------
__global__ __launch_bounds__(512) void agg_kernel(
    const uint32_t* __restrict__ payload, const int* __restrict__ cursor,
    const float* __restrict__ hW, const float* __restrict__ el,
    const float* __restrict__ er, float* __restrict__ out, int N) {
  __shared__ uint32_t sorted[LCAP];  // 18 KB
  __shared__ float exS[LCAP];        // 18 KB
  __shared__ int hist[TILE_NODES];
  __shared__ int pref[TILE_NODES];
  __shared__ int rank[TILE_NODES];

  int t = threadIdx.x;
  int sb = blockIdx.x % SB_SPACING;
  int quad = blockIdx.x / SB_SPACING;
  if (sb >= NBS) return;
  size_t base = (size_t)sb * CAP_SB;
  int cnt = min(cursor[sb * 16], CAP_SB);

  if (t < TILE_NODES) { hist[t] = 0; rank[t] = 0; }
  __syncthreads();

  const uint4* pay4 = (const uint4*)(payload + base);  // 16B-aligned (CAP_SB%4==0)
  int n4 = (cnt + 3) >> 2;
  for (int i = t; i < n4; i += 512) {
    uint4 v = pay4[i];
    int i0 = i << 2;
    if (i0 + 0 < cnt && (int)((v.x >> 7) & 3) == quad) atomicAdd(&hist[v.x & (TILE_NODES - 1)], 1);
    if (i0 + 1 < cnt && (int)((v.y >> 7) & 3) == quad) atomicAdd(&hist[v.y & (TILE_NODES - 1)], 1);
    if (i0 + 2 < cnt && (int)((v.z >> 7) & 3) == quad) atomicAdd(&hist[v.z & (TILE_NODES - 1)], 1);
    if (i0 + 3 < cnt && (int)((v.w >> 7) & 3) == quad) atomicAdd(&hist[v.w & (TILE_NODES - 1)], 1);
  }
  __syncthreads();

  if (t < TILE_NODES) {  // 128-thread O(n) prefix
    int s = 0;
    for (int j = 0; j < t; ++j) s += hist[j];
    pref[t] = s;
  }
  __syncthreads();

  for (int i = t; i < n4; i += 512) {  // re-read (L2-hot) and place
    uint4 v = pay4[i];
    int i0 = i << 2;
#pragma unroll
    for (int j = 0; j < 4; ++j) {
      uint32_t p = j == 0 ? v.x : j == 1 ? v.y : j == 2 ? v.z : v.w;
      if (i0 + j < cnt && (int)((p >> 7) & 3) == quad) {
        int dl = (int)(p & (TILE_NODES - 1));
        int r = atomicAdd(&rank[dl], 1);
        int pos = pref[dl] + r;
        if (pos < LCAP) sorted[pos] = p;
      }
    }
  }
  __syncthreads();

  int node0 = sb * SB_NODES + quad * TILE_NODES;
  int kept = pref[TILE_NODES - 1] + hist[TILE_NODES - 1];
  for (int i = t; i < kept; i += 512) {  // ex computed ONCE per edge
    uint32_t p = sorted[i];
    int s = (int)(p >> SB_BITS);
    float x = el[s] + er[node0 + (int)(p & (TILE_NODES - 1))];
    x = x > 0.f ? x : NEG_SLOPE * x;
    exS[i] = __expf(x);
  }
  __syncthreads();

  int g = t >> 4;  // 32 groups of 16 lanes
  int f = t & 15;
  for (int dl = g; dl < TILE_NODES; dl += 32) {
    int node = node0 + dl;
    if (node >= N) break;
    int k = pref[dl];
    int kend = k + hist[dl];
    float acc = 0.f;
    float es = 0.f;
#pragma unroll 4
    for (; k < kend; ++k) {
      float ex = exS[k];
      acc += ex * hW[(int)(sorted[k] >> SB_BITS) * OUT_F + f];
      es += ex;
    }
    out[(size_t)node * OUT_F + f] = acc / fmaxf(es, 1e-16f);
  }
}

extern "C" void kernel_launch(void* const* d_in, const int* in_sizes, int n_in,
                              void* d_out, int out_size, void* d_ws, size_t ws_size,
                              hipStream_t stream) {
  const float* h   = (const float*)d_in[0];
  const int*   src = (const int*)d_in[1];
  const int*   dst = (const int*)d_in[2];
  const float* W   = (const float*)d_in[3];
  const float* a_l = (const float*)d_in[4];
  const float* a_r = (const float*)d_in[5];
  float* out = (float*)d_out;

  const int N = in_sizes[0] / IN_F;
  const int E = in_sizes[1];
  const int scatBlocks = (E + SC_E - 1) / SC_E;      // 782
  const int projBlocks = (N * OUT_F + 255) / 256;    // 6250

  // ws: hW | el | er | cursor | payload   (payload 16B-aligned by layout)
  float* ws = (float*)d_ws;
  float* hW = ws;                                  // N*16
  float* el = hW + (size_t)N * OUT_F;              // N
  float* er = el + N;                              // N
  int* cursor = (int*)(er + N);                    // NBS*16 (line-strided)
  uint32_t* payload = (uint32_t*)(cursor + (size_t)NBS * 16);  // NBS*CAP_SB

  hipMemsetAsync(cursor, 0, (size_t)NBS * 16 * sizeof(int), stream);

  proj_scatter_kernel<<<scatBlocks + projBlocks, 256, 0, stream>>>(
      h, W, a_l, a_r, src, dst, hW, el, er, cursor, payload, N, E, scatBlocks);

  agg_kernel<<<SB_SPACING * 4, 512, 0, stream>>>(payload, cursor, hW, el, er,
                                                 out, N);
}